// Round 7
// baseline (232.554 us; speedup 1.0000x reference)
//
#include <hip/hip_runtime.h>
#include <hip/hip_bf16.h>
#include <hip/hip_fp16.h>
#include <stdint.h>

#define NROWS 6144
#define MCOLS 6144
#define DDIM  128
#define EPSQ  1e-12f
#define NTC   48          // tiles per side (6144/128)

typedef unsigned long long ull;
typedef __attribute__((ext_vector_type(8))) short short8;
typedef __attribute__((ext_vector_type(4))) float floatx4;

// Order-preserving key: max key == max float value, ties -> smallest index.
__device__ __forceinline__ ull makeKey(float v, int idx) {
    unsigned u = __float_as_uint(v);
    u = (u & 0x80000000u) ? ~u : (u | 0x80000000u);
    return ((ull)u << 32) | (ull)(0xFFFFFFFFu - (unsigned)idx);
}
__device__ __forceinline__ int decodeKeyIdx(ull k) {
    return (int)(0xFFFFFFFFu - (unsigned)(k & 0xFFFFFFFFull));
}
__device__ __forceinline__ unsigned short f2bf(float f) {   // RNE
    unsigned u = __float_as_uint(f);
    u += 0x7fffu + ((u >> 16) & 1);
    return (unsigned short)(u >> 16);
}

#define GLOAD16(g, l) \
  __builtin_amdgcn_global_load_lds((const __attribute__((address_space(1))) unsigned int*)(g), \
                                   (__attribute__((address_space(3))) unsigned int*)(l), 16, 0, 0)

// XCD-chunked tile swizzle: block b -> XCD b%8; give each XCD a contiguous
// run of tile-rows so its L2 keeps the whole s2 panel resident.
__device__ __forceinline__ void tileCoord(int& rowBase, int& colBase) {
    int id  = blockIdx.x;
    int wid = (id & 7) * (NTC * NTC / 8) + (id >> 3);
    rowBase = (wid / NTC) * 128;
    colBase = (wid % NTC) * 128;
}

// ---------------- K0: convert to chunk-major pre-swizzled bf16 panels -------
// Per row 256 bf16: [chunk0: hi(k=0..63)|lo(k=0..63)][chunk1: hi(64..127)|lo].
// Within each 64-elem half, position e' = e ^ ((row&7)<<3).
__global__ __launch_bounds__(256) void convert_kernel(
    const float* __restrict__ d1, const float* __restrict__ d2,
    unsigned short* __restrict__ s1, unsigned short* __restrict__ s2,
    float* __restrict__ sq1, float* __restrict__ sq2)
{
    int gw = (blockIdx.x * 256 + threadIdx.x) >> 6;   // one wave per row
    int lane = threadIdx.x & 63;
    if (gw >= NROWS + MCOLS) return;
    bool isA = gw < NROWS;
    int row = isA ? gw : gw - NROWS;
    const float* src = (isA ? d1 : d2) + (size_t)row * DDIM;
    unsigned short* dst = (isA ? s1 : s2) + (size_t)row * 256;

    float2 v = *(const float2*)(src + lane * 2);
    float s = v.x * v.x + v.y * v.y;
    #pragma unroll
    for (int m = 1; m < 64; m <<= 1) s += __shfl_xor(s, m, 64);
    if (lane == 0) { if (isA) sq1[row] = s; else sq2[row] = s; }

    unsigned short h0 = f2bf(v.x), h1 = f2bf(v.y);
    float r0 = v.x - __uint_as_float((unsigned)h0 << 16);
    float r1 = v.y - __uint_as_float((unsigned)h1 << 16);
    unsigned short l0 = f2bf(r0), l1 = f2bf(r1);
    int c  = lane >> 5;                         // k-chunk (k = 2*lane)
    int e  = (2 * lane) & 63;                   // even; swizzle keeps pair adjacent
    int pe = e ^ ((row & 7) << 3);
    *(unsigned*)(dst + c * 128 + pe)      = (unsigned)h0 | ((unsigned)h1 << 16);
    *(unsigned*)(dst + c * 128 + 64 + pe) = (unsigned)l0 | ((unsigned)l1 << 16);
}

// Compute one 64-K chunk: 3 split passes (hh, lo*hi, hi*lo) x 2 k-steps.
// LDS layout: [128 rows][128] = [hi 64 | lo 64], swizzled within halves.
// SWAPPED operands: mfma(B,A) => lane holds row=l15, cols=(lane>>4)*4+reg.
__device__ __forceinline__ void mfma_chunk_compute(
    const unsigned short* As, const unsigned short* Bs,
    int lane, int wr, int wc, floatx4 acc[4][2])
{
    const int l15 = lane & 15;
    const int q16 = (lane >> 4) * 16;     // byte offset of lane's k-sub
    const int sw  = (l15 & 7) << 4;       // xor swizzle (bytes)
    const char* Ab = (const char*)As;
    const char* Bb = (const char*)Bs;
    int aRowB[4], bRowB[2];
    #pragma unroll
    for (int mi = 0; mi < 4; ++mi) aRowB[mi] = (wr * 64 + mi * 16 + l15) * 256;
    #pragma unroll
    for (int ni = 0; ni < 2; ++ni) bRowB[ni] = (wc * 32 + ni * 16 + l15) * 256;

    #pragma unroll
    for (int p = 0; p < 3; ++p) {
        const int Ah = (p == 1) ? 128 : 0;   // lo half of A (bytes)
        const int Bh = (p == 2) ? 128 : 0;   // lo half of B
        #pragma unroll
        for (int ks = 0; ks < 2; ++ks) {
            const int kk = (ks * 64 + q16) ^ sw;
            short8 af[4], bf[2];
            #pragma unroll
            for (int mi = 0; mi < 4; ++mi)
                af[mi] = *(const short8*)(Ab + aRowB[mi] + Ah + kk);
            #pragma unroll
            for (int ni = 0; ni < 2; ++ni)
                bf[ni] = *(const short8*)(Bb + bRowB[ni] + Bh + kk);
            #pragma unroll
            for (int mi = 0; mi < 4; ++mi)
                #pragma unroll
                for (int ni = 0; ni < 2; ++ni)
                    acc[mi][ni] = __builtin_amdgcn_mfma_f32_16x16x32_bf16(
                        bf[ni], af[mi], acc[mi][ni], 0, 0, 0);   // SWAPPED
        }
    }
}

// Stage-and-compute both chunks. LDS: As/Bs 16K elems (32 KB) each.
__device__ __forceinline__ void mfma_core(
    const unsigned short* __restrict__ s1g, const unsigned short* __restrict__ s2g,
    unsigned short* As, unsigned short* Bs,
    int rowBase, int colBase, int lane, int wave, int wr, int wc,
    floatx4 acc[4][2])
{
    const unsigned short* gA = s1g + (size_t)rowBase * 256;
    const unsigned short* gB = s2g + (size_t)colBase * 256;
    #pragma unroll
    for (int c = 0; c < 2; ++c) {
        if (c) __syncthreads();            // all reads of chunk 0 done
        #pragma unroll
        for (int it = 0; it < 4; ++it) {
            int li = wave * 512 + it * 4096 + lane * 8;    // LDS elem idx
            int gi = li + ((li >> 7) + c) * 128;           // global elem idx
            GLOAD16(gA + gi, &As[li]);
            GLOAD16(gB + gi, &Bs[li]);
        }
        __syncthreads();                   // drains vmcnt before reads
        mfma_chunk_compute(As, Bs, lane, wr, wc, acc);
    }
}

// ---------------- K1: GEMM -> affinity -> reductions + fp16 cache ----------
__global__ __launch_bounds__(512, 4) void gemm_reduce_kernel(
    const unsigned short* __restrict__ s1, const unsigned short* __restrict__ s2,
    const float* __restrict__ invT,
    const float* __restrict__ sq1, const float* __restrict__ sq2,
    unsigned short* __restrict__ affh,          // [N][M] fp16 cache of v
    float* __restrict__ rowsum, float* __restrict__ colsum,
    ull* __restrict__ rowkey, ull* __restrict__ colkey)
{
    __shared__ unsigned short As[128 * 128];   // 32 KB
    __shared__ unsigned short Bs[128 * 128];   // 32 KB
    __shared__ float lRowS[128], lColS[128];
    __shared__ ull   lRowK[128], lColK[128];

    const int t = threadIdx.x;
    const int lane = t & 63;
    const int wave = t >> 6;
    const int wr = wave >> 2, wc = wave & 3;
    int rowBase, colBase;
    tileCoord(rowBase, colBase);

    if (t < 128) { lRowS[t] = 0.f; lColS[t] = 0.f; lRowK[t] = 0ull; lColK[t] = 0ull; }

    floatx4 acc[4][2] = {};
    mfma_core(s1, s2, As, Bs, rowBase, colBase, lane, wave, wr, wc, acc);

    const int l15 = lane & 15;
    const int q   = lane >> 4;
    const float iT = *invT;
    float s1r[4];
    #pragma unroll
    for (int mi = 0; mi < 4; ++mi)
        s1r[mi] = sq1[rowBase + wr * 64 + mi * 16 + l15] + EPSQ;
    const int colLoc0 = wc * 32 + q * 4;
    float4 s2v[2];
    #pragma unroll
    for (int ni = 0; ni < 2; ++ni)
        s2v[ni] = *(const float4*)(sq2 + colBase + colLoc0 + ni * 16);

    float rs[4], rv[4]; int rj[4];
    float cs[2][4], cv[2][4]; int ci[2][4];
    #pragma unroll
    for (int ni = 0; ni < 2; ++ni)
        #pragma unroll
        for (int r = 0; r < 4; ++r) { cs[ni][r] = 0.f; cv[ni][r] = -1e30f; ci[ni][r] = 0; }

    #pragma unroll
    for (int mi = 0; mi < 4; ++mi) {
        const int gi = rowBase + wr * 64 + mi * 16 + l15;
        rs[mi] = 0.f; rv[mi] = -1e30f; rj[mi] = 0;
        #pragma unroll
        for (int ni = 0; ni < 2; ++ni) {
            float vv[4];
            #pragma unroll
            for (int r = 0; r < 4; ++r) {
                float sv2 = (r == 0) ? s2v[ni].x : (r == 1) ? s2v[ni].y
                          : (r == 2) ? s2v[ni].z : s2v[ni].w;
                float dd = s1r[mi] + sv2 - 2.0f * acc[mi][ni][r];
                float v = -iT * __builtin_amdgcn_sqrtf(fmaxf(dd, EPSQ));
                vv[r] = v;
                float e = __expf(v);
                rs[mi] += e;
                if (v > rv[mi]) { rv[mi] = v; rj[mi] = colBase + colLoc0 + ni * 16 + r; }
                cs[ni][r] += e;
                if (v > cv[ni][r]) { cv[ni][r] = v; ci[ni][r] = gi; }
            }
            // fp16 cache write (plain store -> dwells in L2/L3 for K3)
            __half2 ha = __floats2half2_rn(vv[0], vv[1]);
            __half2 hb = __floats2half2_rn(vv[2], vv[3]);
            uint2 u; u.x = *(unsigned*)&ha; u.y = *(unsigned*)&hb;
            *(uint2*)(affh + (size_t)gi * MCOLS + colBase + colLoc0 + ni * 16) = u;
        }
    }

    // row reduce across col-quarters (lanes differing in bits 4,5)
    #pragma unroll
    for (int mi = 0; mi < 4; ++mi) {
        float s = rs[mi], v = rv[mi]; int j = rj[mi];
        #pragma unroll
        for (int m = 16; m < 64; m <<= 1) {
            s += __shfl_xor(s, m, 64);
            float ov = __shfl_xor(v, m, 64);
            int oj = __shfl_xor(j, m, 64);
            if (ov > v || (ov == v && oj < j)) { v = ov; j = oj; }
        }
        if (lane < 16) {
            int idx = wr * 64 + mi * 16 + l15;
            atomicAdd(&lRowS[idx], s);
            atomicMax(&lRowK[idx], makeKey(v, j));
        }
    }

    // col reduce across l15 lanes (rows)
    #pragma unroll
    for (int ni = 0; ni < 2; ++ni)
        #pragma unroll
        for (int r = 0; r < 4; ++r) {
            float s = cs[ni][r], v = cv[ni][r]; int i = ci[ni][r];
            #pragma unroll
            for (int m = 1; m < 16; m <<= 1) {
                s += __shfl_xor(s, m, 64);
                float ov = __shfl_xor(v, m, 64);
                int oi = __shfl_xor(i, m, 64);
                if (ov > v || (ov == v && oi < i)) { v = ov; i = oi; }
            }
            if (l15 == 0) {
                int idx = colLoc0 + ni * 16 + r;
                atomicAdd(&lColS[idx], s);
                atomicMax(&lColK[idx], makeKey(v, i));
            }
        }
    __syncthreads();

    if (t < 128) {
        atomicAdd(&rowsum[rowBase + t], lRowS[t]);
        atomicMax(&rowkey[rowBase + t], lRowK[t]);
    } else if (t < 256) {
        int j = t - 128;
        atomicAdd(&colsum[colBase + j], lColS[j]);
        atomicMax(&colkey[colBase + j], lColK[j]);
    }
}

// ---------------- K2: per-row/col LSE + matches + cycle (merged) ------------
__global__ __launch_bounds__(256) void finalize_small_kernel(
    const float* __restrict__ rowsum, const ull* __restrict__ rowkey,
    const float* __restrict__ colsum, const ull* __restrict__ colkey,
    float* __restrict__ rowlse, float* __restrict__ collse,
    float* __restrict__ out_matches, float* __restrict__ out_cyc)
{
    int i = blockIdx.x * 256 + threadIdx.x;      // N == M
    if (i >= NROWS) return;
    rowlse[i] = logf(rowsum[i]);
    collse[i] = logf(colsum[i]);
    int mi = decodeKeyIdx(rowkey[i]);
    out_matches[i]         = (float)i;
    out_matches[NROWS + i] = (float)mi;
    out_cyc[i] = (decodeKeyIdx(colkey[mi]) == i) ? 1.0f : 0.0f;
}

// ---------------- K3: stream fp16 cache -> dense_logp + dense_p -------------
// 8 elems per thread per iter; reads hit L3 (75 MB cache), writes NT.
__global__ __launch_bounds__(256) void finalize_mat_kernel(
    const unsigned short* __restrict__ affh,
    float* __restrict__ logp_out, float* __restrict__ p_out,
    const float* __restrict__ rowlse, const float* __restrict__ collse)
{
    const size_t total = (size_t)NROWS * MCOLS / 8;
    const size_t stride = (size_t)gridDim.x * 256;
    for (size_t c = (size_t)blockIdx.x * 256 + threadIdx.x; c < total; c += stride) {
        int i  = (int)(c / (MCOLS / 8));
        int jq = (int)(c % (MCOLS / 8));
        float rl = rowlse[i];
        float4 cl0 = *(const float4*)(collse + jq * 8);
        float4 cl1 = *(const float4*)(collse + jq * 8 + 4);
        uint4 u = *(const uint4*)(affh + c * 8);
        float2 f0 = __half22float2(*(const __half2*)&u.x);
        float2 f1 = __half22float2(*(const __half2*)&u.y);
        float2 f2 = __half22float2(*(const __half2*)&u.z);
        float2 f3 = __half22float2(*(const __half2*)&u.w);
        floatx4 o0, o1, p0, p1;
        o0[0] = 2.0f * f0.x - rl - cl0.x;  p0[0] = __expf(o0[0]);
        o0[1] = 2.0f * f0.y - rl - cl0.y;  p0[1] = __expf(o0[1]);
        o0[2] = 2.0f * f1.x - rl - cl0.z;  p0[2] = __expf(o0[2]);
        o0[3] = 2.0f * f1.y - rl - cl0.w;  p0[3] = __expf(o0[3]);
        o1[0] = 2.0f * f2.x - rl - cl1.x;  p1[0] = __expf(o1[0]);
        o1[1] = 2.0f * f2.y - rl - cl1.y;  p1[1] = __expf(o1[1]);
        o1[2] = 2.0f * f3.x - rl - cl1.z;  p1[2] = __expf(o1[2]);
        o1[3] = 2.0f * f3.y - rl - cl1.w;  p1[3] = __expf(o1[3]);
        __builtin_nontemporal_store(o0, (floatx4*)(logp_out + c * 8));
        __builtin_nontemporal_store(o1, (floatx4*)(logp_out + c * 8 + 4));
        __builtin_nontemporal_store(p0, (floatx4*)(p_out + c * 8));
        __builtin_nontemporal_store(p1, (floatx4*)(p_out + c * 8 + 4));
    }
}

extern "C" void kernel_launch(void* const* d_in, const int* in_sizes, int n_in,
                              void* d_out, int out_size, void* d_ws, size_t ws_size,
                              hipStream_t stream) {
    const float* d1   = (const float*)d_in[0];
    const float* d2   = (const float*)d_in[1];
    const float* invT = (const float*)d_in[2];

    float* out     = (float*)d_out;
    float* logp    = out;
    float* pout    = out + (size_t)NROWS * MCOLS;
    float* matches = out + 2ull * NROWS * MCOLS;
    float* cyc     = matches + 2 * NROWS;

    char* ws = (char*)d_ws;
    float* rowsum = (float*)(ws + 0);
    float* colsum = (float*)(ws + 24576);
    ull*   rowkey = (ull*)(ws + 49152);
    ull*   colkey = (ull*)(ws + 98304);
    float* sq1    = (float*)(ws + 147456);
    float* sq2    = (float*)(ws + 172032);
    float* rowlse = (float*)(ws + 196608);
    float* collse = (float*)(ws + 221184);
    unsigned short* s1   = (unsigned short*)(ws + 270336);            // [N][256] bf16
    unsigned short* s2   = (unsigned short*)(ws + 270336 + 3145728);  // [M][256] bf16
    unsigned short* affh = (unsigned short*)(ws + 270336 + 6291456);  // [N][M] fp16, 75.5 MB

    (void)hipMemsetAsync(d_ws, 0, 147456, stream);     // rowsum/colsum/rowkey/colkey

    convert_kernel<<<(NROWS + MCOLS) / 4, 256, 0, stream>>>(d1, d2, s1, s2, sq1, sq2);

    gemm_reduce_kernel<<<NTC * NTC, 512, 0, stream>>>(
        s1, s2, invT, sq1, sq2, affh, rowsum, colsum, rowkey, colkey);

    finalize_small_kernel<<<NROWS / 256, 256, 0, stream>>>(
        rowsum, rowkey, colsum, colkey, rowlse, collse, matches, cyc);

    finalize_mat_kernel<<<2048, 256, 0, stream>>>(
        affh, logp, pout, rowlse, collse);
}

// Round 8
// 207.182 us; speedup vs baseline: 1.1225x; 1.1225x over previous
//
#include <hip/hip_runtime.h>
#include <hip/hip_bf16.h>
#include <stdint.h>

#define NROWS 6144
#define MCOLS 6144
#define DDIM  128
#define EPSQ  1e-12f
#define NTC   48          // tiles per side (6144/128)

typedef unsigned long long ull;
typedef __attribute__((ext_vector_type(8))) short short8;
typedef __attribute__((ext_vector_type(4))) float floatx4;

// Order-preserving key: max key == max float value, ties -> smallest index.
__device__ __forceinline__ ull makeKey(float v, int idx) {
    unsigned u = __float_as_uint(v);
    u = (u & 0x80000000u) ? ~u : (u | 0x80000000u);
    return ((ull)u << 32) | (ull)(0xFFFFFFFFu - (unsigned)idx);
}
__device__ __forceinline__ int decodeKeyIdx(ull k) {
    return (int)(0xFFFFFFFFu - (unsigned)(k & 0xFFFFFFFFull));
}
__device__ __forceinline__ unsigned short f2bf(float f) {   // RNE
    unsigned u = __float_as_uint(f);
    u += 0x7fffu + ((u >> 16) & 1);
    return (unsigned short)(u >> 16);
}

#define GLOAD16(g, l) \
  __builtin_amdgcn_global_load_lds((const __attribute__((address_space(1))) unsigned int*)(g), \
                                   (__attribute__((address_space(3))) unsigned int*)(l), 16, 0, 0)

// XCD-chunked tile swizzle: block b -> XCD b%8; give each XCD a contiguous
// run of tile-rows so its L2 keeps the whole s2 panel resident.
__device__ __forceinline__ void tileCoord(int& rowBase, int& colBase) {
    int id  = blockIdx.x;
    int wid = (id & 7) * (NTC * NTC / 8) + (id >> 3);
    rowBase = (wid / NTC) * 128;
    colBase = (wid % NTC) * 128;
}

// ---------------- K0: convert to chunk-major pre-swizzled bf16 panels -------
// Per row 256 bf16: [chunk0: hi(k=0..63)|lo(k=0..63)][chunk1: hi(64..127)|lo].
// Within each 64-elem half, position e' = e ^ ((row&7)<<3).
__global__ __launch_bounds__(256) void convert_kernel(
    const float* __restrict__ d1, const float* __restrict__ d2,
    unsigned short* __restrict__ s1, unsigned short* __restrict__ s2,
    float* __restrict__ sq1, float* __restrict__ sq2)
{
    int gw = (blockIdx.x * 256 + threadIdx.x) >> 6;   // one wave per row
    int lane = threadIdx.x & 63;
    if (gw >= NROWS + MCOLS) return;
    bool isA = gw < NROWS;
    int row = isA ? gw : gw - NROWS;
    const float* src = (isA ? d1 : d2) + (size_t)row * DDIM;
    unsigned short* dst = (isA ? s1 : s2) + (size_t)row * 256;

    float2 v = *(const float2*)(src + lane * 2);
    float s = v.x * v.x + v.y * v.y;
    #pragma unroll
    for (int m = 1; m < 64; m <<= 1) s += __shfl_xor(s, m, 64);
    if (lane == 0) { if (isA) sq1[row] = s; else sq2[row] = s; }

    unsigned short h0 = f2bf(v.x), h1 = f2bf(v.y);
    float r0 = v.x - __uint_as_float((unsigned)h0 << 16);
    float r1 = v.y - __uint_as_float((unsigned)h1 << 16);
    unsigned short l0 = f2bf(r0), l1 = f2bf(r1);
    int c  = lane >> 5;                         // k-chunk (k = 2*lane)
    int e  = (2 * lane) & 63;                   // even; swizzle keeps pair adjacent
    int pe = e ^ ((row & 7) << 3);
    *(unsigned*)(dst + c * 128 + pe)      = (unsigned)h0 | ((unsigned)h1 << 16);
    *(unsigned*)(dst + c * 128 + 64 + pe) = (unsigned)l0 | ((unsigned)l1 << 16);
}

// Compute one 64-K chunk: 3 split passes (hh, lo*hi, hi*lo) x 2 k-steps.
// LDS layout: [128 rows][128] = [hi 64 | lo 64], swizzled within halves.
// SWAPPED operands: mfma(B,A) => lane holds row=l15, cols=(lane>>4)*4+reg.
__device__ __forceinline__ void mfma_chunk_compute(
    const unsigned short* As, const unsigned short* Bs,
    int lane, int wr, int wc, floatx4 acc[4][2])
{
    const int l15 = lane & 15;
    const int q16 = (lane >> 4) * 16;     // byte offset of lane's k-sub
    const int sw  = (l15 & 7) << 4;       // xor swizzle (bytes)
    const char* Ab = (const char*)As;
    const char* Bb = (const char*)Bs;
    int aRowB[4], bRowB[2];
    #pragma unroll
    for (int mi = 0; mi < 4; ++mi) aRowB[mi] = (wr * 64 + mi * 16 + l15) * 256;
    #pragma unroll
    for (int ni = 0; ni < 2; ++ni) bRowB[ni] = (wc * 32 + ni * 16 + l15) * 256;

    #pragma unroll
    for (int p = 0; p < 3; ++p) {
        const int Ah = (p == 1) ? 128 : 0;   // lo half of A (bytes)
        const int Bh = (p == 2) ? 128 : 0;   // lo half of B
        #pragma unroll
        for (int ks = 0; ks < 2; ++ks) {
            const int kk = (ks * 64 + q16) ^ sw;
            short8 af[4], bf[2];
            #pragma unroll
            for (int mi = 0; mi < 4; ++mi)
                af[mi] = *(const short8*)(Ab + aRowB[mi] + Ah + kk);
            #pragma unroll
            for (int ni = 0; ni < 2; ++ni)
                bf[ni] = *(const short8*)(Bb + bRowB[ni] + Bh + kk);
            #pragma unroll
            for (int mi = 0; mi < 4; ++mi)
                #pragma unroll
                for (int ni = 0; ni < 2; ++ni)
                    acc[mi][ni] = __builtin_amdgcn_mfma_f32_16x16x32_bf16(
                        bf[ni], af[mi], acc[mi][ni], 0, 0, 0);   // SWAPPED
        }
    }
}

// Stage-and-compute both chunks with parallel staging:
// chunk0 -> LDS DMA, chunk1(A) -> regs at the same time; both drain at bar 1.
__device__ __forceinline__ void mfma_core(
    const unsigned short* __restrict__ s1g, const unsigned short* __restrict__ s2g,
    unsigned short* As, unsigned short* Bs,
    int rowBase, int colBase, int lane, int wave, int wr, int wc,
    floatx4 acc[4][2])
{
    const unsigned short* gA = s1g + (size_t)rowBase * 256;
    const unsigned short* gB = s2g + (size_t)colBase * 256;

    // chunk0 -> LDS (DMA)
    #pragma unroll
    for (int it = 0; it < 4; ++it) {
        int l = wave * 512 + it * 4096 + lane * 8;
        int g0 = l + (l >> 7) * 128;
        GLOAD16(gA + g0, &As[l]);
        GLOAD16(gB + g0, &Bs[l]);
    }
    // chunk1 A -> regs (latency overlaps chunk0 DMA; both drained at barrier)
    uint4 apre[4];
    #pragma unroll
    for (int it = 0; it < 4; ++it) {
        int l = wave * 512 + it * 4096 + lane * 8;
        int g1 = l + ((l >> 7) + 1) * 128;
        apre[it] = *(const uint4*)(gA + g1);
    }
    __syncthreads();

    mfma_chunk_compute(As, Bs, lane, wr, wc, acc);
    __syncthreads();

    // chunk1: B -> LDS DMA first (in flight during A ds_writes)
    #pragma unroll
    for (int it = 0; it < 4; ++it) {
        int l = wave * 512 + it * 4096 + lane * 8;
        int g1 = l + ((l >> 7) + 1) * 128;
        GLOAD16(gB + g1, &Bs[l]);
    }
    #pragma unroll
    for (int it = 0; it < 4; ++it) {
        int l = wave * 512 + it * 4096 + lane * 8;
        *(uint4*)(&As[l]) = apre[it];
    }
    __syncthreads();

    mfma_chunk_compute(As, Bs, lane, wr, wc, acc);
}

// ---------------- K1: GEMM -> affinity -> row/col reductions ONLY ----------
__global__ __launch_bounds__(512, 4) void gemm_reduce_kernel(
    const unsigned short* __restrict__ s1, const unsigned short* __restrict__ s2,
    const float* __restrict__ invT,
    const float* __restrict__ sq1, const float* __restrict__ sq2,
    float* __restrict__ rowsum, float* __restrict__ colsum,
    ull* __restrict__ rowkey, ull* __restrict__ colkey)
{
    __shared__ unsigned short As[128 * 128];   // 32 KB
    __shared__ unsigned short Bs[128 * 128];   // 32 KB
    __shared__ float lRowS[128], lColS[128];
    __shared__ ull   lRowK[128], lColK[128];

    const int t = threadIdx.x;
    const int lane = t & 63;
    const int wave = t >> 6;
    const int wr = wave >> 2, wc = wave & 3;
    int rowBase, colBase;
    tileCoord(rowBase, colBase);

    if (t < 128) { lRowS[t] = 0.f; lColS[t] = 0.f; lRowK[t] = 0ull; lColK[t] = 0ull; }

    floatx4 acc[4][2] = {};
    mfma_core(s1, s2, As, Bs, rowBase, colBase, lane, wave, wr, wc, acc);

    const int l15 = lane & 15;
    const int q   = lane >> 4;
    const float iT = *invT;
    float s1r[4];
    #pragma unroll
    for (int mi = 0; mi < 4; ++mi)
        s1r[mi] = sq1[rowBase + wr * 64 + mi * 16 + l15] + EPSQ;
    const int colLoc0 = wc * 32 + q * 4;
    float4 s2v[2];
    #pragma unroll
    for (int ni = 0; ni < 2; ++ni)
        s2v[ni] = *(const float4*)(sq2 + colBase + colLoc0 + ni * 16);

    float rs[4], rv[4]; int rj[4];
    float cs[2][4], cv[2][4]; int ci[2][4];
    #pragma unroll
    for (int ni = 0; ni < 2; ++ni)
        #pragma unroll
        for (int r = 0; r < 4; ++r) { cs[ni][r] = 0.f; cv[ni][r] = -1e30f; ci[ni][r] = 0; }

    #pragma unroll
    for (int mi = 0; mi < 4; ++mi) {
        const int gi = rowBase + wr * 64 + mi * 16 + l15;
        rs[mi] = 0.f; rv[mi] = -1e30f; rj[mi] = 0;
        #pragma unroll
        for (int ni = 0; ni < 2; ++ni) {
            #pragma unroll
            for (int r = 0; r < 4; ++r) {
                float sv2 = (r == 0) ? s2v[ni].x : (r == 1) ? s2v[ni].y
                          : (r == 2) ? s2v[ni].z : s2v[ni].w;
                float dd = s1r[mi] + sv2 - 2.0f * acc[mi][ni][r];
                float v = -iT * __builtin_amdgcn_sqrtf(fmaxf(dd, EPSQ));
                float e = __expf(v);
                rs[mi] += e;
                if (v > rv[mi]) { rv[mi] = v; rj[mi] = colBase + colLoc0 + ni * 16 + r; }
                cs[ni][r] += e;
                if (v > cv[ni][r]) { cv[ni][r] = v; ci[ni][r] = gi; }
            }
        }
    }

    // row reduce across col-quarters (lanes differing in bits 4,5)
    #pragma unroll
    for (int mi = 0; mi < 4; ++mi) {
        float s = rs[mi], v = rv[mi]; int j = rj[mi];
        #pragma unroll
        for (int m = 16; m < 64; m <<= 1) {
            s += __shfl_xor(s, m, 64);
            float ov = __shfl_xor(v, m, 64);
            int oj = __shfl_xor(j, m, 64);
            if (ov > v || (ov == v && oj < j)) { v = ov; j = oj; }
        }
        if (lane < 16) {
            int idx = wr * 64 + mi * 16 + l15;
            atomicAdd(&lRowS[idx], s);
            atomicMax(&lRowK[idx], makeKey(v, j));
        }
    }

    // col reduce across l15 lanes (rows)
    #pragma unroll
    for (int ni = 0; ni < 2; ++ni)
        #pragma unroll
        for (int r = 0; r < 4; ++r) {
            float s = cs[ni][r], v = cv[ni][r]; int i = ci[ni][r];
            #pragma unroll
            for (int m = 1; m < 16; m <<= 1) {
                s += __shfl_xor(s, m, 64);
                float ov = __shfl_xor(v, m, 64);
                int oi = __shfl_xor(i, m, 64);
                if (ov > v || (ov == v && oi < i)) { v = ov; i = oi; }
            }
            if (l15 == 0) {
                int idx = colLoc0 + ni * 16 + r;
                atomicAdd(&lColS[idx], s);
                atomicMax(&lColK[idx], makeKey(v, i));
            }
        }
    __syncthreads();

    if (t < 128) {
        atomicAdd(&rowsum[rowBase + t], lRowS[t]);
        atomicMax(&rowkey[rowBase + t], lRowK[t]);
    } else if (t < 256) {
        int j = t - 128;
        atomicAdd(&colsum[colBase + j], lColS[j]);
        atomicMax(&colkey[colBase + j], lColK[j]);
    }
}

// ---------------- K2: per-row/col LSE + matches + cycle (merged) ------------
__global__ __launch_bounds__(256) void finalize_small_kernel(
    const float* __restrict__ rowsum, const ull* __restrict__ rowkey,
    const float* __restrict__ colsum, const ull* __restrict__ colkey,
    float* __restrict__ rowlse, float* __restrict__ collse,
    float* __restrict__ out_matches, float* __restrict__ out_cyc)
{
    int i = blockIdx.x * 256 + threadIdx.x;      // N == M
    if (i >= NROWS) return;
    rowlse[i] = logf(rowsum[i]);
    collse[i] = logf(colsum[i]);
    int mi = decodeKeyIdx(rowkey[i]);
    out_matches[i]         = (float)i;
    out_matches[NROWS + i] = (float)mi;
    out_cyc[i] = (decodeKeyIdx(colkey[mi]) == i) ? 1.0f : 0.0f;
}

// ---------------- K3: GEMM again -> write dense_logp + dense_p --------------
__global__ __launch_bounds__(512, 4) void gemm_write_kernel(
    const unsigned short* __restrict__ s1, const unsigned short* __restrict__ s2,
    const float* __restrict__ invT,
    const float* __restrict__ sq1, const float* __restrict__ sq2,
    const float* __restrict__ rowlse, const float* __restrict__ collse,
    float* __restrict__ logp_out, float* __restrict__ p_out)
{
    __shared__ unsigned short As[128 * 128];   // 32 KB
    __shared__ unsigned short Bs[128 * 128];   // 32 KB

    const int t = threadIdx.x;
    const int lane = t & 63;
    const int wave = t >> 6;
    const int wr = wave >> 2, wc = wave & 3;
    int rowBase, colBase;
    tileCoord(rowBase, colBase);

    floatx4 acc[4][2] = {};
    mfma_core(s1, s2, As, Bs, rowBase, colBase, lane, wave, wr, wc, acc);

    const int l15 = lane & 15;
    const int q   = lane >> 4;
    const float iT = *invT;
    float s1r[4], rl[4];
    #pragma unroll
    for (int mi = 0; mi < 4; ++mi) {
        int gi = rowBase + wr * 64 + mi * 16 + l15;
        s1r[mi] = sq1[gi] + EPSQ;
        rl[mi]  = rowlse[gi];
    }
    const int colLoc0 = wc * 32 + q * 4;
    float4 s2v[2], clv[2];
    #pragma unroll
    for (int ni = 0; ni < 2; ++ni) {
        s2v[ni] = *(const float4*)(sq2    + colBase + colLoc0 + ni * 16);
        clv[ni] = *(const float4*)(collse + colBase + colLoc0 + ni * 16);
    }

    #pragma unroll
    for (int mi = 0; mi < 4; ++mi) {
        const int gi = rowBase + wr * 64 + mi * 16 + l15;
        #pragma unroll
        for (int ni = 0; ni < 2; ++ni) {
            floatx4 ov, pv;
            #pragma unroll
            for (int r = 0; r < 4; ++r) {
                float sv2 = (r == 0) ? s2v[ni].x : (r == 1) ? s2v[ni].y
                          : (r == 2) ? s2v[ni].z : s2v[ni].w;
                float cl  = (r == 0) ? clv[ni].x : (r == 1) ? clv[ni].y
                          : (r == 2) ? clv[ni].z : clv[ni].w;
                float dd = s1r[mi] + sv2 - 2.0f * acc[mi][ni][r];
                float v = -iT * __builtin_amdgcn_sqrtf(fmaxf(dd, EPSQ));
                float o = (v - rl[mi]) + (v - cl);
                ov[r] = o;
                pv[r] = __expf(o);
            }
            size_t off = (size_t)gi * MCOLS + colBase + colLoc0 + ni * 16;
            *(floatx4*)(logp_out + off) = ov;    // plain stores (NT reverted)
            *(floatx4*)(p_out + off)    = pv;
        }
    }
}

extern "C" void kernel_launch(void* const* d_in, const int* in_sizes, int n_in,
                              void* d_out, int out_size, void* d_ws, size_t ws_size,
                              hipStream_t stream) {
    const float* d1   = (const float*)d_in[0];
    const float* d2   = (const float*)d_in[1];
    const float* invT = (const float*)d_in[2];

    float* out     = (float*)d_out;
    float* logp    = out;
    float* pout    = out + (size_t)NROWS * MCOLS;
    float* matches = out + 2ull * NROWS * MCOLS;
    float* cyc     = matches + 2 * NROWS;

    char* ws = (char*)d_ws;
    float* rowsum = (float*)(ws + 0);
    float* colsum = (float*)(ws + 24576);
    ull*   rowkey = (ull*)(ws + 49152);
    ull*   colkey = (ull*)(ws + 98304);
    float* sq1    = (float*)(ws + 147456);
    float* sq2    = (float*)(ws + 172032);
    float* rowlse = (float*)(ws + 196608);
    float* collse = (float*)(ws + 221184);
    unsigned short* s1 = (unsigned short*)(ws + 270336);            // [N][256] bf16
    unsigned short* s2 = (unsigned short*)(ws + 270336 + 3145728);  // [M][256] bf16

    (void)hipMemsetAsync(d_ws, 0, 147456, stream);     // rowsum/colsum/rowkey/colkey

    convert_kernel<<<(NROWS + MCOLS) / 4, 256, 0, stream>>>(d1, d2, s1, s2, sq1, sq2);

    gemm_reduce_kernel<<<NTC * NTC, 512, 0, stream>>>(
        s1, s2, invT, sq1, sq2, rowsum, colsum, rowkey, colkey);

    finalize_small_kernel<<<NROWS / 256, 256, 0, stream>>>(
        rowsum, rowkey, colsum, colkey, rowlse, collse, matches, cyc);

    gemm_write_kernel<<<NTC * NTC, 512, 0, stream>>>(
        s1, s2, invT, sq1, sq2, rowlse, collse, logp, pout);
}

// Round 9
// 174.091 us; speedup vs baseline: 1.3358x; 1.1901x over previous
//
#include <hip/hip_runtime.h>
#include <hip/hip_bf16.h>
#include <stdint.h>

#define NROWS 6144
#define MCOLS 6144
#define DDIM  128
#define EPSQ  1e-12f
#define NTC   48          // tiles per side (6144/128)

typedef unsigned long long ull;
typedef __attribute__((ext_vector_type(8))) short short8;
typedef __attribute__((ext_vector_type(4))) float floatx4;

// Order-preserving key: max key == max float value, ties -> smallest index.
__device__ __forceinline__ ull makeKey(float v, int idx) {
    unsigned u = __float_as_uint(v);
    u = (u & 0x80000000u) ? ~u : (u | 0x80000000u);
    return ((ull)u << 32) | (ull)(0xFFFFFFFFu - (unsigned)idx);
}
__device__ __forceinline__ int decodeKeyIdx(ull k) {
    return (int)(0xFFFFFFFFu - (unsigned)(k & 0xFFFFFFFFull));
}
__device__ __forceinline__ unsigned short f2bf(float f) {   // RNE
    unsigned u = __float_as_uint(f);
    u += 0x7fffu + ((u >> 16) & 1);
    return (unsigned short)(u >> 16);
}

#define GLOAD16(g, l) \
  __builtin_amdgcn_global_load_lds((const __attribute__((address_space(1))) unsigned int*)(g), \
                                   (__attribute__((address_space(3))) unsigned int*)(l), 16, 0, 0)

// XCD-chunked tile swizzle: block b -> XCD b%8; give each XCD a contiguous
// run of tile-rows so its L2 keeps the whole s2 panel resident.
__device__ __forceinline__ void tileCoord(int& rowBase, int& colBase) {
    int id  = blockIdx.x;
    int wid = (id & 7) * (NTC * NTC / 8) + (id >> 3);
    rowBase = (wid / NTC) * 128;
    colBase = (wid % NTC) * 128;
}

// ---------------- K0: convert to chunk-major pre-swizzled bf16 panels -------
// Per row 256 bf16: [chunk0: hi(k=0..63)|lo(k=0..63)][chunk1: hi(64..127)|lo].
// Within each 64-elem half, position e' = e ^ ((row&7)<<3).
// Also zero-inits the 147456-byte atomic accumulator region (replaces memset).
__global__ __launch_bounds__(256) void convert_kernel(
    const float* __restrict__ d1, const float* __restrict__ d2,
    unsigned short* __restrict__ s1, unsigned short* __restrict__ s2,
    float* __restrict__ sq1, float* __restrict__ sq2,
    unsigned* __restrict__ zero_region)
{
    int tid = blockIdx.x * 256 + threadIdx.x;
    if (tid < 36864) zero_region[tid] = 0u;           // rowsum/colsum/rowkey/colkey

    int gw = tid >> 6;                                 // one wave per row
    int lane = threadIdx.x & 63;
    if (gw >= NROWS + MCOLS) return;
    bool isA = gw < NROWS;
    int row = isA ? gw : gw - NROWS;
    const float* src = (isA ? d1 : d2) + (size_t)row * DDIM;
    unsigned short* dst = (isA ? s1 : s2) + (size_t)row * 256;

    float2 v = *(const float2*)(src + lane * 2);
    float s = v.x * v.x + v.y * v.y;
    #pragma unroll
    for (int m = 1; m < 64; m <<= 1) s += __shfl_xor(s, m, 64);
    if (lane == 0) { if (isA) sq1[row] = s; else sq2[row] = s; }

    unsigned short h0 = f2bf(v.x), h1 = f2bf(v.y);
    float r0 = v.x - __uint_as_float((unsigned)h0 << 16);
    float r1 = v.y - __uint_as_float((unsigned)h1 << 16);
    unsigned short l0 = f2bf(r0), l1 = f2bf(r1);
    int c  = lane >> 5;                         // k-chunk (k = 2*lane)
    int e  = (2 * lane) & 63;                   // even; swizzle keeps pair adjacent
    int pe = e ^ ((row & 7) << 3);
    *(unsigned*)(dst + c * 128 + pe)      = (unsigned)h0 | ((unsigned)h1 << 16);
    *(unsigned*)(dst + c * 128 + 64 + pe) = (unsigned)l0 | ((unsigned)l1 << 16);
}

// ======== 3-split core (reduce pass) — R6-proven, unchanged ========
// Compute one 64-K chunk: 3 split passes (hh, lo*hi, hi*lo) x 2 k-steps.
// LDS layout: [128 rows][128] = [hi 64 | lo 64], swizzled within halves.
// SWAPPED operands: mfma(B,A) => lane holds row=l15, cols=(lane>>4)*4+reg.
__device__ __forceinline__ void mfma_chunk_compute(
    const unsigned short* As, const unsigned short* Bs,
    int lane, int wr, int wc, floatx4 acc[4][2])
{
    const int l15 = lane & 15;
    const int q16 = (lane >> 4) * 16;     // byte offset of lane's k-sub
    const int sw  = (l15 & 7) << 4;       // xor swizzle (bytes)
    const char* Ab = (const char*)As;
    const char* Bb = (const char*)Bs;
    int aRowB[4], bRowB[2];
    #pragma unroll
    for (int mi = 0; mi < 4; ++mi) aRowB[mi] = (wr * 64 + mi * 16 + l15) * 256;
    #pragma unroll
    for (int ni = 0; ni < 2; ++ni) bRowB[ni] = (wc * 32 + ni * 16 + l15) * 256;

    #pragma unroll
    for (int p = 0; p < 3; ++p) {
        const int Ah = (p == 1) ? 128 : 0;   // lo half of A (bytes)
        const int Bh = (p == 2) ? 128 : 0;   // lo half of B
        #pragma unroll
        for (int ks = 0; ks < 2; ++ks) {
            const int kk = (ks * 64 + q16) ^ sw;
            short8 af[4], bf[2];
            #pragma unroll
            for (int mi = 0; mi < 4; ++mi)
                af[mi] = *(const short8*)(Ab + aRowB[mi] + Ah + kk);
            #pragma unroll
            for (int ni = 0; ni < 2; ++ni)
                bf[ni] = *(const short8*)(Bb + bRowB[ni] + Bh + kk);
            #pragma unroll
            for (int mi = 0; mi < 4; ++mi)
                #pragma unroll
                for (int ni = 0; ni < 2; ++ni)
                    acc[mi][ni] = __builtin_amdgcn_mfma_f32_16x16x32_bf16(
                        bf[ni], af[mi], acc[mi][ni], 0, 0, 0);   // SWAPPED
        }
    }
}

__device__ __forceinline__ void mfma_core(
    const unsigned short* __restrict__ s1g, const unsigned short* __restrict__ s2g,
    unsigned short* As, unsigned short* Bs,
    int rowBase, int colBase, int lane, int wave, int wr, int wc,
    floatx4 acc[4][2])
{
    const unsigned short* gA = s1g + (size_t)rowBase * 256;
    const unsigned short* gB = s2g + (size_t)colBase * 256;
    #pragma unroll
    for (int c = 0; c < 2; ++c) {
        if (c) __syncthreads();            // all reads of chunk 0 done
        #pragma unroll
        for (int it = 0; it < 4; ++it) {
            int li = wave * 512 + it * 4096 + lane * 8;    // LDS elem idx
            int gi = li + ((li >> 7) + c) * 128;           // global elem idx
            GLOAD16(gA + gi, &As[li]);
            GLOAD16(gB + gi, &Bs[li]);
        }
        __syncthreads();                   // drains vmcnt before reads
        mfma_chunk_compute(As, Bs, lane, wr, wc, acc);
    }
}

// ======== 2-split core (write pass): inner ~= ah*bh + al*bh = a*bh ========
// A: [128][128] per chunk (hi|lo).  B: hi only, [128][64] per chunk, both
// chunks staged up front.  Error ~1e-4 in inner -> ~1e-3 in logp (tolerated).
__device__ __forceinline__ void mfma_chunk_compute_2s(
    const unsigned short* As, const unsigned short* Bs,   // Bs: one chunk [128][64]
    int lane, int wr, int wc, floatx4 acc[4][2])
{
    const int l15 = lane & 15;
    const int q16 = (lane >> 4) * 16;
    const int sw  = (l15 & 7) << 4;
    const char* Ab = (const char*)As;
    const char* Bb = (const char*)Bs;
    int aRowB[4], bRowB[2];
    #pragma unroll
    for (int mi = 0; mi < 4; ++mi) aRowB[mi] = (wr * 64 + mi * 16 + l15) * 256;
    #pragma unroll
    for (int ni = 0; ni < 2; ++ni) bRowB[ni] = (wc * 32 + ni * 16 + l15) * 128;

    #pragma unroll
    for (int p = 0; p < 2; ++p) {
        const int Ah = p * 128;              // 0: hi*bh, 1: lo*bh
        #pragma unroll
        for (int ks = 0; ks < 2; ++ks) {
            const int kk = (ks * 64 + q16) ^ sw;
            short8 af[4], bf[2];
            #pragma unroll
            for (int mi = 0; mi < 4; ++mi)
                af[mi] = *(const short8*)(Ab + aRowB[mi] + Ah + kk);
            #pragma unroll
            for (int ni = 0; ni < 2; ++ni)
                bf[ni] = *(const short8*)(Bb + bRowB[ni] + kk);
            #pragma unroll
            for (int mi = 0; mi < 4; ++mi)
                #pragma unroll
                for (int ni = 0; ni < 2; ++ni)
                    acc[mi][ni] = __builtin_amdgcn_mfma_f32_16x16x32_bf16(
                        bf[ni], af[mi], acc[mi][ni], 0, 0, 0);
        }
    }
}

__device__ __forceinline__ void mfma_core_w(
    const unsigned short* __restrict__ s1g, const unsigned short* __restrict__ s2g,
    unsigned short* As, unsigned short* Bs0, unsigned short* Bs1,
    int rowBase, int colBase, int lane, int wave, int wr, int wc,
    floatx4 acc[4][2])
{
    const unsigned short* gA = s1g + (size_t)rowBase * 256;
    const unsigned short* gB = s2g + (size_t)colBase * 256;

    // A chunk0 (4 loads) + B-hi both chunks (2+2 loads)
    #pragma unroll
    for (int it = 0; it < 4; ++it) {
        int li = wave * 512 + it * 4096 + lane * 8;
        int gi = li + (li >> 7) * 128;
        GLOAD16(gA + gi, &As[li]);
    }
    #pragma unroll
    for (int it = 0; it < 2; ++it) {
        int lb = wave * 512 + it * 4096 + lane * 8;        // [0,8192)
        int gb = lb + (lb >> 6) * 192;                     // chunk0 hi
        GLOAD16(gB + gb, &Bs0[lb]);
        GLOAD16(gB + gb + 128, &Bs1[lb]);                  // chunk1 hi
    }
    __syncthreads();
    mfma_chunk_compute_2s(As, Bs0, lane, wr, wc, acc);
    __syncthreads();
    #pragma unroll
    for (int it = 0; it < 4; ++it) {
        int li = wave * 512 + it * 4096 + lane * 8;
        int gi = li + ((li >> 7) + 1) * 128;               // A chunk1
        GLOAD16(gA + gi, &As[li]);
    }
    __syncthreads();
    mfma_chunk_compute_2s(As, Bs1, lane, wr, wc, acc);
}

// ---------------- K1: GEMM -> affinity -> row/col reductions ONLY ----------
__global__ __launch_bounds__(512, 4) void gemm_reduce_kernel(
    const unsigned short* __restrict__ s1, const unsigned short* __restrict__ s2,
    const float* __restrict__ invT,
    const float* __restrict__ sq1, const float* __restrict__ sq2,
    float* __restrict__ rowsum, float* __restrict__ colsum,
    ull* __restrict__ rowkey, ull* __restrict__ colkey)
{
    __shared__ unsigned short As[128 * 128];   // 32 KB
    __shared__ unsigned short Bs[128 * 128];   // 32 KB
    __shared__ float lRowS[128], lColS[128];
    __shared__ ull   lRowK[128], lColK[128];

    const int t = threadIdx.x;
    const int lane = t & 63;
    const int wave = t >> 6;
    const int wr = wave >> 2, wc = wave & 3;
    int rowBase, colBase;
    tileCoord(rowBase, colBase);

    if (t < 128) { lRowS[t] = 0.f; lColS[t] = 0.f; lRowK[t] = 0ull; lColK[t] = 0ull; }

    floatx4 acc[4][2] = {};
    mfma_core(s1, s2, As, Bs, rowBase, colBase, lane, wave, wr, wc, acc);

    const int l15 = lane & 15;
    const int q   = lane >> 4;
    const float iT = *invT;
    float s1r[4];
    #pragma unroll
    for (int mi = 0; mi < 4; ++mi)
        s1r[mi] = sq1[rowBase + wr * 64 + mi * 16 + l15] + EPSQ;
    const int colLoc0 = wc * 32 + q * 4;
    float4 s2v[2];
    #pragma unroll
    for (int ni = 0; ni < 2; ++ni)
        s2v[ni] = *(const float4*)(sq2 + colBase + colLoc0 + ni * 16);

    float rs[4], rv[4]; int rj[4];
    float cs[2][4], cv[2][4]; int ci[2][4];
    #pragma unroll
    for (int ni = 0; ni < 2; ++ni)
        #pragma unroll
        for (int r = 0; r < 4; ++r) { cs[ni][r] = 0.f; cv[ni][r] = -1e30f; ci[ni][r] = 0; }

    #pragma unroll
    for (int mi = 0; mi < 4; ++mi) {
        const int gi = rowBase + wr * 64 + mi * 16 + l15;
        rs[mi] = 0.f; rv[mi] = -1e30f; rj[mi] = 0;
        #pragma unroll
        for (int ni = 0; ni < 2; ++ni) {
            #pragma unroll
            for (int r = 0; r < 4; ++r) {
                float sv2 = (r == 0) ? s2v[ni].x : (r == 1) ? s2v[ni].y
                          : (r == 2) ? s2v[ni].z : s2v[ni].w;
                float dd = s1r[mi] + sv2 - 2.0f * acc[mi][ni][r];
                float v = -iT * __builtin_amdgcn_sqrtf(fmaxf(dd, EPSQ));
                float e = __expf(v);
                rs[mi] += e;
                if (v > rv[mi]) { rv[mi] = v; rj[mi] = colBase + colLoc0 + ni * 16 + r; }
                cs[ni][r] += e;
                if (v > cv[ni][r]) { cv[ni][r] = v; ci[ni][r] = gi; }
            }
        }
    }

    // row reduce across col-quarters (lanes differing in bits 4,5)
    #pragma unroll
    for (int mi = 0; mi < 4; ++mi) {
        float s = rs[mi], v = rv[mi]; int j = rj[mi];
        #pragma unroll
        for (int m = 16; m < 64; m <<= 1) {
            s += __shfl_xor(s, m, 64);
            float ov = __shfl_xor(v, m, 64);
            int oj = __shfl_xor(j, m, 64);
            if (ov > v || (ov == v && oj < j)) { v = ov; j = oj; }
        }
        if (lane < 16) {
            int idx = wr * 64 + mi * 16 + l15;
            atomicAdd(&lRowS[idx], s);
            atomicMax(&lRowK[idx], makeKey(v, j));
        }
    }

    // col reduce across l15 lanes (rows)
    #pragma unroll
    for (int ni = 0; ni < 2; ++ni)
        #pragma unroll
        for (int r = 0; r < 4; ++r) {
            float s = cs[ni][r], v = cv[ni][r]; int i = ci[ni][r];
            #pragma unroll
            for (int m = 1; m < 16; m <<= 1) {
                s += __shfl_xor(s, m, 64);
                float ov = __shfl_xor(v, m, 64);
                int oi = __shfl_xor(i, m, 64);
                if (ov > v || (ov == v && oi < i)) { v = ov; i = oi; }
            }
            if (l15 == 0) {
                int idx = colLoc0 + ni * 16 + r;
                atomicAdd(&lColS[idx], s);
                atomicMax(&lColK[idx], makeKey(v, i));
            }
        }
    __syncthreads();

    if (t < 128) {
        atomicAdd(&rowsum[rowBase + t], lRowS[t]);
        atomicMax(&rowkey[rowBase + t], lRowK[t]);
    } else if (t < 256) {
        int j = t - 128;
        atomicAdd(&colsum[colBase + j], lColS[j]);
        atomicMax(&colkey[colBase + j], lColK[j]);
    }
}

// ---------------- K2: per-row/col LSE + matches + cycle (merged) ------------
__global__ __launch_bounds__(256) void finalize_small_kernel(
    const float* __restrict__ rowsum, const ull* __restrict__ rowkey,
    const float* __restrict__ colsum, const ull* __restrict__ colkey,
    float* __restrict__ rowlse, float* __restrict__ collse,
    float* __restrict__ out_matches, float* __restrict__ out_cyc)
{
    int i = blockIdx.x * 256 + threadIdx.x;      // N == M
    if (i >= NROWS) return;
    rowlse[i] = logf(rowsum[i]);
    collse[i] = logf(colsum[i]);
    int mi = decodeKeyIdx(rowkey[i]);
    out_matches[i]         = (float)i;
    out_matches[NROWS + i] = (float)mi;
    out_cyc[i] = (decodeKeyIdx(colkey[mi]) == i) ? 1.0f : 0.0f;
}

// ---------------- K3: 2-split GEMM -> write dense_logp + dense_p ------------
__global__ __launch_bounds__(512, 4) void gemm_write_kernel(
    const unsigned short* __restrict__ s1, const unsigned short* __restrict__ s2,
    const float* __restrict__ invT,
    const float* __restrict__ sq1, const float* __restrict__ sq2,
    const float* __restrict__ rowlse, const float* __restrict__ collse,
    float* __restrict__ logp_out, float* __restrict__ p_out)
{
    __shared__ unsigned short As[128 * 128];    // 32 KB
    __shared__ unsigned short Bs0[128 * 64];    // 16 KB (chunk0 B-hi)
    __shared__ unsigned short Bs1[128 * 64];    // 16 KB (chunk1 B-hi)

    const int t = threadIdx.x;
    const int lane = t & 63;
    const int wave = t >> 6;
    const int wr = wave >> 2, wc = wave & 3;
    int rowBase, colBase;
    tileCoord(rowBase, colBase);

    floatx4 acc[4][2] = {};
    mfma_core_w(s1, s2, As, Bs0, Bs1, rowBase, colBase, lane, wave, wr, wc, acc);

    const int l15 = lane & 15;
    const int q   = lane >> 4;
    const float iT = *invT;
    float s1r[4], rl[4];
    #pragma unroll
    for (int mi = 0; mi < 4; ++mi) {
        int gi = rowBase + wr * 64 + mi * 16 + l15;
        s1r[mi] = sq1[gi] + EPSQ;
        rl[mi]  = rowlse[gi];
    }
    const int colLoc0 = wc * 32 + q * 4;
    float4 s2v[2], clv[2];
    #pragma unroll
    for (int ni = 0; ni < 2; ++ni) {
        s2v[ni] = *(const float4*)(sq2    + colBase + colLoc0 + ni * 16);
        clv[ni] = *(const float4*)(collse + colBase + colLoc0 + ni * 16);
    }

    #pragma unroll
    for (int mi = 0; mi < 4; ++mi) {
        const int gi = rowBase + wr * 64 + mi * 16 + l15;
        #pragma unroll
        for (int ni = 0; ni < 2; ++ni) {
            floatx4 ov, pv;
            #pragma unroll
            for (int r = 0; r < 4; ++r) {
                float sv2 = (r == 0) ? s2v[ni].x : (r == 1) ? s2v[ni].y
                          : (r == 2) ? s2v[ni].z : s2v[ni].w;
                float cl  = (r == 0) ? clv[ni].x : (r == 1) ? clv[ni].y
                          : (r == 2) ? clv[ni].z : clv[ni].w;
                float dd = s1r[mi] + sv2 - 2.0f * acc[mi][ni][r];
                float v = -iT * __builtin_amdgcn_sqrtf(fmaxf(dd, EPSQ));
                float o = (v - rl[mi]) + (v - cl);
                ov[r] = o;
                pv[r] = __expf(o);
            }
            size_t off = (size_t)gi * MCOLS + colBase + colLoc0 + ni * 16;
            __builtin_nontemporal_store(ov, (floatx4*)(logp_out + off));
            __builtin_nontemporal_store(pv, (floatx4*)(p_out + off));
        }
    }
}

extern "C" void kernel_launch(void* const* d_in, const int* in_sizes, int n_in,
                              void* d_out, int out_size, void* d_ws, size_t ws_size,
                              hipStream_t stream) {
    const float* d1   = (const float*)d_in[0];
    const float* d2   = (const float*)d_in[1];
    const float* invT = (const float*)d_in[2];

    float* out     = (float*)d_out;
    float* logp    = out;
    float* pout    = out + (size_t)NROWS * MCOLS;
    float* matches = out + 2ull * NROWS * MCOLS;
    float* cyc     = matches + 2 * NROWS;

    char* ws = (char*)d_ws;
    float* rowsum = (float*)(ws + 0);
    float* colsum = (float*)(ws + 24576);
    ull*   rowkey = (ull*)(ws + 49152);
    ull*   colkey = (ull*)(ws + 98304);
    float* sq1    = (float*)(ws + 147456);
    float* sq2    = (float*)(ws + 172032);
    float* rowlse = (float*)(ws + 196608);
    float* collse = (float*)(ws + 221184);
    unsigned short* s1 = (unsigned short*)(ws + 270336);            // [N][256] bf16
    unsigned short* s2 = (unsigned short*)(ws + 270336 + 3145728);  // [M][256] bf16

    convert_kernel<<<(NROWS + MCOLS) / 4, 256, 0, stream>>>(
        d1, d2, s1, s2, sq1, sq2, (unsigned*)ws);

    gemm_reduce_kernel<<<NTC * NTC, 512, 0, stream>>>(
        s1, s2, invT, sq1, sq2, rowsum, colsum, rowkey, colkey);

    finalize_small_kernel<<<NROWS / 256, 256, 0, stream>>>(
        rowsum, rowkey, colsum, colkey, rowlse, collse, matches, cyc);

    gemm_write_kernel<<<NTC * NTC, 512, 0, stream>>>(
        s1, s2, invT, sq1, sq2, rowlse, collse, logp, pout);
}

// Round 10
// 171.619 us; speedup vs baseline: 1.3551x; 1.0144x over previous
//
#include <hip/hip_runtime.h>
#include <hip/hip_bf16.h>
#include <stdint.h>

#define NROWS 6144
#define MCOLS 6144
#define DDIM  128
#define EPSQ  1e-12f
#define NTC   48          // tiles per side (6144/128)

typedef unsigned long long ull;
typedef __attribute__((ext_vector_type(8))) short short8;
typedef __attribute__((ext_vector_type(4))) float floatx4;

// Order-preserving key: max key == max float value, ties -> smallest index.
__device__ __forceinline__ ull makeKey(float v, int idx) {
    unsigned u = __float_as_uint(v);
    u = (u & 0x80000000u) ? ~u : (u | 0x80000000u);
    return ((ull)u << 32) | (ull)(0xFFFFFFFFu - (unsigned)idx);
}
__device__ __forceinline__ int decodeKeyIdx(ull k) {
    return (int)(0xFFFFFFFFu - (unsigned)(k & 0xFFFFFFFFull));
}
__device__ __forceinline__ unsigned short f2bf(float f) {   // RNE
    unsigned u = __float_as_uint(f);
    u += 0x7fffu + ((u >> 16) & 1);
    return (unsigned short)(u >> 16);
}

#define GLOAD16(g, l) \
  __builtin_amdgcn_global_load_lds((const __attribute__((address_space(1))) unsigned int*)(g), \
                                   (__attribute__((address_space(3))) unsigned int*)(l), 16, 0, 0)

// XCD-chunked tile swizzle: block b -> XCD b%8; give each XCD a contiguous
// run of tile-rows so its L2 keeps the whole s2 panel resident.
__device__ __forceinline__ void tileCoord(int& rowBase, int& colBase) {
    int id  = blockIdx.x;
    int wid = (id & 7) * (NTC * NTC / 8) + (id >> 3);
    rowBase = (wid / NTC) * 128;
    colBase = (wid % NTC) * 128;
}

// ---------------- K0: convert to chunk-major pre-swizzled bf16 panels -------
// Per row 256 bf16: [c0: hi(k0..63)|lo(k0..63)][c1: hi|lo]; within each
// 64-elem half, position e' = e ^ ((row&7)<<3).
// Also zero-inits the 147456-byte atomic accumulator region.
__global__ __launch_bounds__(256) void convert_kernel(
    const float* __restrict__ d1, const float* __restrict__ d2,
    unsigned short* __restrict__ s1, unsigned short* __restrict__ s2,
    float* __restrict__ sq1, float* __restrict__ sq2,
    unsigned* __restrict__ zero_region)
{
    int tid = blockIdx.x * 256 + threadIdx.x;
    if (tid < 36864) zero_region[tid] = 0u;           // rowsum/colsum/rowkey/colkey

    int gw = tid >> 6;                                 // one wave per row
    int lane = threadIdx.x & 63;
    if (gw >= NROWS + MCOLS) return;
    bool isA = gw < NROWS;
    int row = isA ? gw : gw - NROWS;
    const float* src = (isA ? d1 : d2) + (size_t)row * DDIM;
    unsigned short* dst = (isA ? s1 : s2) + (size_t)row * 256;

    float2 v = *(const float2*)(src + lane * 2);
    float s = v.x * v.x + v.y * v.y;
    #pragma unroll
    for (int m = 1; m < 64; m <<= 1) s += __shfl_xor(s, m, 64);
    if (lane == 0) { if (isA) sq1[row] = s; else sq2[row] = s; }

    unsigned short h0 = f2bf(v.x), h1 = f2bf(v.y);
    float r0 = v.x - __uint_as_float((unsigned)h0 << 16);
    float r1 = v.y - __uint_as_float((unsigned)h1 << 16);
    unsigned short l0 = f2bf(r0), l1 = f2bf(r1);
    int c  = lane >> 5;                         // k-chunk (k = 2*lane)
    int e  = (2 * lane) & 63;                   // even; swizzle keeps pair adjacent
    int pe = e ^ ((row & 7) << 3);
    *(unsigned*)(dst + c * 128 + pe)      = (unsigned)h0 | ((unsigned)h1 << 16);
    *(unsigned*)(dst + c * 128 + 64 + pe) = (unsigned)l0 | ((unsigned)l1 << 16);
}

// Stage one 16KB half-panel (128 rows x 64 elems) of (chunk c, half h) -> buf.
// LDS dest is linear (wave-uniform base + lane*16B); global src pre-swizzled.
__device__ __forceinline__ void stageBuf(
    const unsigned short* __restrict__ gpanel, unsigned short* buf,
    int c, int h, int t)
{
    #pragma unroll
    for (int it = 0; it < 2; ++it) {
        int li = t * 8 + it * 4096;                 // elem idx in [0, 8192)
        int r  = li >> 6, e = li & 63;
        int gi = r * 256 + c * 128 + h * 64 + e;
        GLOAD16(gpanel + gi, &buf[li]);
    }
}

// One split-product pass over a 64-K chunk: 2 k-steps x 8 MFMA.
// Buffers are [128 rows][64 elems], row stride 128 B.
// SWAPPED operands: mfma(B,A) => lane holds row=l15, cols=(lane>>4)*4+reg.
__device__ __forceinline__ void computeSplit(
    const unsigned short* Ab_, const unsigned short* Bb_,
    int lane, int wr, int wc, floatx4 acc[4][2])
{
    const int l15 = lane & 15;
    const int q16 = (lane >> 4) * 16;     // byte offset of lane's k-sub
    const int sw  = (l15 & 7) << 4;       // xor swizzle (bytes)
    const char* Ab = (const char*)Ab_;
    const char* Bb = (const char*)Bb_;
    #pragma unroll
    for (int ks = 0; ks < 2; ++ks) {
        const int kk = (ks * 64 + q16) ^ sw;
        short8 af[4], bf[2];
        #pragma unroll
        for (int mi = 0; mi < 4; ++mi)
            af[mi] = *(const short8*)(Ab + (wr * 64 + mi * 16 + l15) * 128 + kk);
        #pragma unroll
        for (int ni = 0; ni < 2; ++ni)
            bf[ni] = *(const short8*)(Bb + (wc * 32 + ni * 16 + l15) * 128 + kk);
        #pragma unroll
        for (int mi = 0; mi < 4; ++mi)
            #pragma unroll
            for (int ni = 0; ni < 2; ++ni)
                acc[mi][ni] = __builtin_amdgcn_mfma_f32_16x16x32_bf16(
                    bf[ni], af[mi], acc[mi][ni], 0, 0, 0);   // SWAPPED
    }
}

// ---------------- K1: 3-split GEMM (pipelined) -> affinity -> reductions ----
__global__ __launch_bounds__(512, 4) void gemm_reduce_kernel(
    const unsigned short* __restrict__ s1, const unsigned short* __restrict__ s2,
    const float* __restrict__ invT,
    const float* __restrict__ sq1, const float* __restrict__ sq2,
    float* __restrict__ rowsum, float* __restrict__ colsum,
    ull* __restrict__ rowkey, ull* __restrict__ colkey)
{
    __shared__ unsigned short A0[8192], A1[8192], B0[8192], B1[8192];  // 4x16KB
    __shared__ float lRowS[128], lColS[128];
    __shared__ ull   lRowK[128], lColK[128];

    const int t = threadIdx.x;
    const int lane = t & 63;
    const int wave = t >> 6;
    const int wr = wave >> 2, wc = wave & 3;
    int rowBase, colBase;
    tileCoord(rowBase, colBase);
    const unsigned short* gA = s1 + (size_t)rowBase * 256;
    const unsigned short* gB = s2 + (size_t)colBase * 256;

    if (t < 128) { lRowS[t] = 0.f; lColS[t] = 0.f; lRowK[t] = 0ull; lColK[t] = 0ull; }

    floatx4 acc[4][2] = {};
    // ---- pipelined 3-split x 2 chunks (hh, hl, lh per chunk) ----
    stageBuf(gA, A0, 0, 0, t); stageBuf(gB, B0, 0, 0, t);      // c0 Ah, Bh
    __syncthreads();
    stageBuf(gA, A1, 0, 1, t); stageBuf(gB, B1, 0, 1, t);      // c0 Al, Bl
    computeSplit(A0, B0, lane, wr, wc, acc);                   // c0 hh
    __syncthreads();
    computeSplit(A0, B1, lane, wr, wc, acc);                   // c0 hl
    __syncthreads();
    stageBuf(gA, A0, 1, 0, t); stageBuf(gB, B1, 1, 0, t);      // c1 Ah, Bh
    computeSplit(A1, B0, lane, wr, wc, acc);                   // c0 lh
    __syncthreads();
    stageBuf(gA, A1, 1, 1, t); stageBuf(gB, B0, 1, 1, t);      // c1 Al, Bl
    computeSplit(A0, B1, lane, wr, wc, acc);                   // c1 hh
    __syncthreads();
    computeSplit(A0, B0, lane, wr, wc, acc);                   // c1 hl
    computeSplit(A1, B1, lane, wr, wc, acc);                   // c1 lh

    // ---- epilogue (unchanged) ----
    const int l15 = lane & 15;
    const int q   = lane >> 4;
    const float iT = *invT;
    float s1r[4];
    #pragma unroll
    for (int mi = 0; mi < 4; ++mi)
        s1r[mi] = sq1[rowBase + wr * 64 + mi * 16 + l15] + EPSQ;
    const int colLoc0 = wc * 32 + q * 4;
    float4 s2v[2];
    #pragma unroll
    for (int ni = 0; ni < 2; ++ni)
        s2v[ni] = *(const float4*)(sq2 + colBase + colLoc0 + ni * 16);

    float rs[4], rv[4]; int rj[4];
    float cs[2][4], cv[2][4]; int ci[2][4];
    #pragma unroll
    for (int ni = 0; ni < 2; ++ni)
        #pragma unroll
        for (int r = 0; r < 4; ++r) { cs[ni][r] = 0.f; cv[ni][r] = -1e30f; ci[ni][r] = 0; }

    #pragma unroll
    for (int mi = 0; mi < 4; ++mi) {
        const int gi = rowBase + wr * 64 + mi * 16 + l15;
        rs[mi] = 0.f; rv[mi] = -1e30f; rj[mi] = 0;
        #pragma unroll
        for (int ni = 0; ni < 2; ++ni) {
            #pragma unroll
            for (int r = 0; r < 4; ++r) {
                float sv2 = (r == 0) ? s2v[ni].x : (r == 1) ? s2v[ni].y
                          : (r == 2) ? s2v[ni].z : s2v[ni].w;
                float dd = s1r[mi] + sv2 - 2.0f * acc[mi][ni][r];
                float v = -iT * __builtin_amdgcn_sqrtf(fmaxf(dd, EPSQ));
                float e = __expf(v);
                rs[mi] += e;
                if (v > rv[mi]) { rv[mi] = v; rj[mi] = colBase + colLoc0 + ni * 16 + r; }
                cs[ni][r] += e;
                if (v > cv[ni][r]) { cv[ni][r] = v; ci[ni][r] = gi; }
            }
        }
    }

    // row reduce across col-quarters (lanes differing in bits 4,5)
    #pragma unroll
    for (int mi = 0; mi < 4; ++mi) {
        float s = rs[mi], v = rv[mi]; int j = rj[mi];
        #pragma unroll
        for (int m = 16; m < 64; m <<= 1) {
            s += __shfl_xor(s, m, 64);
            float ov = __shfl_xor(v, m, 64);
            int oj = __shfl_xor(j, m, 64);
            if (ov > v || (ov == v && oj < j)) { v = ov; j = oj; }
        }
        if (lane < 16) {
            int idx = wr * 64 + mi * 16 + l15;
            atomicAdd(&lRowS[idx], s);
            atomicMax(&lRowK[idx], makeKey(v, j));
        }
    }

    // col reduce across l15 lanes (rows)
    #pragma unroll
    for (int ni = 0; ni < 2; ++ni)
        #pragma unroll
        for (int r = 0; r < 4; ++r) {
            float s = cs[ni][r], v = cv[ni][r]; int i = ci[ni][r];
            #pragma unroll
            for (int m = 1; m < 16; m <<= 1) {
                s += __shfl_xor(s, m, 64);
                float ov = __shfl_xor(v, m, 64);
                int oi = __shfl_xor(i, m, 64);
                if (ov > v || (ov == v && oi < i)) { v = ov; i = oi; }
            }
            if (l15 == 0) {
                int idx = colLoc0 + ni * 16 + r;
                atomicAdd(&lColS[idx], s);
                atomicMax(&lColK[idx], makeKey(v, i));
            }
        }
    __syncthreads();

    if (t < 128) {
        atomicAdd(&rowsum[rowBase + t], lRowS[t]);
        atomicMax(&rowkey[rowBase + t], lRowK[t]);
    } else if (t < 256) {
        int j = t - 128;
        atomicAdd(&colsum[colBase + j], lColS[j]);
        atomicMax(&colkey[colBase + j], lColK[j]);
    }
}

// ---------------- K2: per-row/col LSE + matches + cycle (merged) ------------
__global__ __launch_bounds__(256) void finalize_small_kernel(
    const float* __restrict__ rowsum, const ull* __restrict__ rowkey,
    const float* __restrict__ colsum, const ull* __restrict__ colkey,
    float* __restrict__ rowlse, float* __restrict__ collse,
    float* __restrict__ out_matches, float* __restrict__ out_cyc)
{
    int i = blockIdx.x * 256 + threadIdx.x;      // N == M
    if (i >= NROWS) return;
    rowlse[i] = logf(rowsum[i]);
    collse[i] = logf(colsum[i]);
    int mi = decodeKeyIdx(rowkey[i]);
    out_matches[i]         = (float)i;
    out_matches[NROWS + i] = (float)mi;
    out_cyc[i] = (decodeKeyIdx(colkey[mi]) == i) ? 1.0f : 0.0f;
}

// ---------------- K3: 2-split GEMM (pipelined) -> write logp + p ------------
__global__ __launch_bounds__(512, 4) void gemm_write_kernel(
    const unsigned short* __restrict__ s1, const unsigned short* __restrict__ s2,
    const float* __restrict__ invT,
    const float* __restrict__ sq1, const float* __restrict__ sq2,
    const float* __restrict__ rowlse, const float* __restrict__ collse,
    float* __restrict__ logp_out, float* __restrict__ p_out)
{
    __shared__ unsigned short A0[8192], A1[8192], B0[8192], B1[8192];  // 4x16KB

    const int t = threadIdx.x;
    const int lane = t & 63;
    const int wave = t >> 6;
    const int wr = wave >> 2, wc = wave & 3;
    int rowBase, colBase;
    tileCoord(rowBase, colBase);
    const unsigned short* gA = s1 + (size_t)rowBase * 256;
    const unsigned short* gB = s2 + (size_t)colBase * 256;

    floatx4 acc[4][2] = {};
    // ---- pipelined 2-split (a*bh = ah*bh + al*bh) x 2 chunks ----
    stageBuf(gA, A0, 0, 0, t); stageBuf(gB, B0, 0, 0, t);      // c0 Ah, Bh
    __syncthreads();
    stageBuf(gA, A1, 0, 1, t); stageBuf(gB, B1, 1, 0, t);      // c0 Al, c1 Bh
    computeSplit(A0, B0, lane, wr, wc, acc);                   // c0 hh
    __syncthreads();
    stageBuf(gA, A0, 1, 0, t);                                 // c1 Ah
    computeSplit(A1, B0, lane, wr, wc, acc);                   // c0 lh
    __syncthreads();
    stageBuf(gA, A1, 1, 1, t);                                 // c1 Al
    computeSplit(A0, B1, lane, wr, wc, acc);                   // c1 hh
    __syncthreads();
    computeSplit(A1, B1, lane, wr, wc, acc);                   // c1 lh

    const int l15 = lane & 15;
    const int q   = lane >> 4;
    const float iT = *invT;
    float s1r[4], rl[4];
    #pragma unroll
    for (int mi = 0; mi < 4; ++mi) {
        int gi = rowBase + wr * 64 + mi * 16 + l15;
        s1r[mi] = sq1[gi] + EPSQ;
        rl[mi]  = rowlse[gi];
    }
    const int colLoc0 = wc * 32 + q * 4;
    float4 s2v[2], clv[2];
    #pragma unroll
    for (int ni = 0; ni < 2; ++ni) {
        s2v[ni] = *(const float4*)(sq2    + colBase + colLoc0 + ni * 16);
        clv[ni] = *(const float4*)(collse + colBase + colLoc0 + ni * 16);
    }

    #pragma unroll
    for (int mi = 0; mi < 4; ++mi) {
        const int gi = rowBase + wr * 64 + mi * 16 + l15;
        #pragma unroll
        for (int ni = 0; ni < 2; ++ni) {
            floatx4 ov, pv;
            #pragma unroll
            for (int r = 0; r < 4; ++r) {
                float sv2 = (r == 0) ? s2v[ni].x : (r == 1) ? s2v[ni].y
                          : (r == 2) ? s2v[ni].z : s2v[ni].w;
                float cl  = (r == 0) ? clv[ni].x : (r == 1) ? clv[ni].y
                          : (r == 2) ? clv[ni].z : clv[ni].w;
                float dd = s1r[mi] + sv2 - 2.0f * acc[mi][ni][r];
                float v = -iT * __builtin_amdgcn_sqrtf(fmaxf(dd, EPSQ));
                float o = (v - rl[mi]) + (v - cl);
                ov[r] = o;
                pv[r] = __expf(o);
            }
            size_t off = (size_t)gi * MCOLS + colBase + colLoc0 + ni * 16;
            __builtin_nontemporal_store(ov, (floatx4*)(logp_out + off));
            __builtin_nontemporal_store(pv, (floatx4*)(p_out + off));
        }
    }
}

extern "C" void kernel_launch(void* const* d_in, const int* in_sizes, int n_in,
                              void* d_out, int out_size, void* d_ws, size_t ws_size,
                              hipStream_t stream) {
    const float* d1   = (const float*)d_in[0];
    const float* d2   = (const float*)d_in[1];
    const float* invT = (const float*)d_in[2];

    float* out     = (float*)d_out;
    float* logp    = out;
    float* pout    = out + (size_t)NROWS * MCOLS;
    float* matches = out + 2ull * NROWS * MCOLS;
    float* cyc     = matches + 2 * NROWS;

    char* ws = (char*)d_ws;
    float* rowsum = (float*)(ws + 0);
    float* colsum = (float*)(ws + 24576);
    ull*   rowkey = (ull*)(ws + 49152);
    ull*   colkey = (ull*)(ws + 98304);
    float* sq1    = (float*)(ws + 147456);
    float* sq2    = (float*)(ws + 172032);
    float* rowlse = (float*)(ws + 196608);
    float* collse = (float*)(ws + 221184);
    unsigned short* s1 = (unsigned short*)(ws + 270336);            // [N][256] bf16
    unsigned short* s2 = (unsigned short*)(ws + 270336 + 3145728);  // [M][256] bf16

    convert_kernel<<<(NROWS + MCOLS) / 4, 256, 0, stream>>>(
        d1, d2, s1, s2, sq1, sq2, (unsigned*)ws);

    gemm_reduce_kernel<<<NTC * NTC, 512, 0, stream>>>(
        s1, s2, invT, sq1, sq2, rowsum, colsum, rowkey, colkey);

    finalize_small_kernel<<<NROWS / 256, 256, 0, stream>>>(
        rowsum, rowkey, colsum, colkey, rowlse, collse, matches, cyc);

    gemm_write_kernel<<<NTC * NTC, 512, 0, stream>>>(
        s1, s2, invT, sq1, sq2, rowlse, collse, logp, pout);
}

// Round 11
// 157.207 us; speedup vs baseline: 1.4793x; 1.0917x over previous
//
#include <hip/hip_runtime.h>
#include <hip/hip_bf16.h>
#include <stdint.h>

#define NROWS 6144
#define MCOLS 6144
#define DDIM  128
#define EPSQ  1e-12f
#define NTC   48          // tiles per side (6144/128)

typedef unsigned long long ull;
typedef __attribute__((ext_vector_type(8))) short short8;
typedef __attribute__((ext_vector_type(4))) float floatx4;

// Order-preserving key: max key == max float value, ties -> smallest index.
__device__ __forceinline__ ull makeKey(float v, int idx) {
    unsigned u = __float_as_uint(v);
    u = (u & 0x80000000u) ? ~u : (u | 0x80000000u);
    return ((ull)u << 32) | (ull)(0xFFFFFFFFu - (unsigned)idx);
}
__device__ __forceinline__ int decodeKeyIdx(ull k) {
    return (int)(0xFFFFFFFFu - (unsigned)(k & 0xFFFFFFFFull));
}
__device__ __forceinline__ unsigned short f2bf(float f) {   // RNE
    unsigned u = __float_as_uint(f);
    u += 0x7fffu + ((u >> 16) & 1);
    return (unsigned short)(u >> 16);
}

// DPP cross-lane within 16-lane rows (VALU pipe, not LDS).
#define DPPF(x, ctrl) __uint_as_float(__builtin_amdgcn_update_dpp( \
    0, (int)__float_as_uint(x), (ctrl), 0xF, 0xF, false))
#define DPPI(x, ctrl) __builtin_amdgcn_update_dpp(0, (x), (ctrl), 0xF, 0xF, false)
// row_ror:N encodings
#define ROR8 0x128
#define ROR4 0x124
#define ROR2 0x122
#define ROR1 0x121

#define GLOAD16(g, l) \
  __builtin_amdgcn_global_load_lds((const __attribute__((address_space(1))) unsigned int*)(g), \
                                   (__attribute__((address_space(3))) unsigned int*)(l), 16, 0, 0)

// XCD-chunked tile swizzle: block b -> XCD b%8; give each XCD a contiguous
// run of tile-rows so its L2 keeps the whole s2 panel resident.
__device__ __forceinline__ void tileCoord(int& rowBase, int& colBase) {
    int id  = blockIdx.x;
    int wid = (id & 7) * (NTC * NTC / 8) + (id >> 3);
    rowBase = (wid / NTC) * 128;
    colBase = (wid % NTC) * 128;
}

// ---------------- K0: convert to chunk-major pre-swizzled bf16 panels -------
__global__ __launch_bounds__(256) void convert_kernel(
    const float* __restrict__ d1, const float* __restrict__ d2,
    unsigned short* __restrict__ s1, unsigned short* __restrict__ s2,
    float* __restrict__ sq1, float* __restrict__ sq2,
    unsigned* __restrict__ zero_region)
{
    int tid = blockIdx.x * 256 + threadIdx.x;
    if (tid < 36864) zero_region[tid] = 0u;           // rowsum/colsum/rowkey/colkey

    int gw = tid >> 6;                                 // one wave per row
    int lane = threadIdx.x & 63;
    if (gw >= NROWS + MCOLS) return;
    bool isA = gw < NROWS;
    int row = isA ? gw : gw - NROWS;
    const float* src = (isA ? d1 : d2) + (size_t)row * DDIM;
    unsigned short* dst = (isA ? s1 : s2) + (size_t)row * 256;

    float2 v = *(const float2*)(src + lane * 2);
    float s = v.x * v.x + v.y * v.y;
    #pragma unroll
    for (int m = 1; m < 64; m <<= 1) s += __shfl_xor(s, m, 64);
    if (lane == 0) { if (isA) sq1[row] = s; else sq2[row] = s; }

    unsigned short h0 = f2bf(v.x), h1 = f2bf(v.y);
    float r0 = v.x - __uint_as_float((unsigned)h0 << 16);
    float r1 = v.y - __uint_as_float((unsigned)h1 << 16);
    unsigned short l0 = f2bf(r0), l1 = f2bf(r1);
    int c  = lane >> 5;                         // k-chunk (k = 2*lane)
    int e  = (2 * lane) & 63;                   // even; swizzle keeps pair adjacent
    int pe = e ^ ((row & 7) << 3);
    *(unsigned*)(dst + c * 128 + pe)      = (unsigned)h0 | ((unsigned)h1 << 16);
    *(unsigned*)(dst + c * 128 + 64 + pe) = (unsigned)l0 | ((unsigned)l1 << 16);
}

// Stage one 16KB half-panel (128 rows x 64 elems) of (chunk c, half h) -> buf.
__device__ __forceinline__ void stageBuf(
    const unsigned short* __restrict__ gpanel, unsigned short* buf,
    int c, int h, int t)
{
    #pragma unroll
    for (int it = 0; it < 2; ++it) {
        int li = t * 8 + it * 4096;                 // elem idx in [0, 8192)
        int r  = li >> 6, e = li & 63;
        int gi = r * 256 + c * 128 + h * 64 + e;
        GLOAD16(gpanel + gi, &buf[li]);
    }
}

// One split-product pass over a 64-K chunk: 2 k-steps x 8 MFMA.
// SWAPPED operands: mfma(B,A) => lane holds row=l15, cols=(lane>>4)*4+reg.
__device__ __forceinline__ void computeSplit(
    const unsigned short* Ab_, const unsigned short* Bb_,
    int lane, int wr, int wc, floatx4 acc[4][2])
{
    const int l15 = lane & 15;
    const int q16 = (lane >> 4) * 16;     // byte offset of lane's k-sub
    const int sw  = (l15 & 7) << 4;       // xor swizzle (bytes)
    const char* Ab = (const char*)Ab_;
    const char* Bb = (const char*)Bb_;
    #pragma unroll
    for (int ks = 0; ks < 2; ++ks) {
        const int kk = (ks * 64 + q16) ^ sw;
        short8 af[4], bf[2];
        #pragma unroll
        for (int mi = 0; mi < 4; ++mi)
            af[mi] = *(const short8*)(Ab + (wr * 64 + mi * 16 + l15) * 128 + kk);
        #pragma unroll
        for (int ni = 0; ni < 2; ++ni)
            bf[ni] = *(const short8*)(Bb + (wc * 32 + ni * 16 + l15) * 128 + kk);
        #pragma unroll
        for (int mi = 0; mi < 4; ++mi)
            #pragma unroll
            for (int ni = 0; ni < 2; ++ni)
                acc[mi][ni] = __builtin_amdgcn_mfma_f32_16x16x32_bf16(
                    bf[ni], af[mi], acc[mi][ni], 0, 0, 0);   // SWAPPED
    }
}

// ---------------- K1: 3-split GEMM (pipelined) -> affinity -> reductions ----
__global__ __launch_bounds__(512, 4) void gemm_reduce_kernel(
    const unsigned short* __restrict__ s1, const unsigned short* __restrict__ s2,
    const float* __restrict__ invT,
    const float* __restrict__ sq1, const float* __restrict__ sq2,
    float* __restrict__ rowsum, float* __restrict__ colsum,
    ull* __restrict__ rowkey, ull* __restrict__ colkey)
{
    __shared__ unsigned short A0[8192], A1[8192], B0[8192], B1[8192];  // 4x16KB
    __shared__ float lRowS[128], lColS[128];
    __shared__ ull   lRowK[128], lColK[128];

    const int t = threadIdx.x;
    const int lane = t & 63;
    const int wave = t >> 6;
    const int wr = wave >> 2, wc = wave & 3;
    int rowBase, colBase;
    tileCoord(rowBase, colBase);
    const unsigned short* gA = s1 + (size_t)rowBase * 256;
    const unsigned short* gB = s2 + (size_t)colBase * 256;

    if (t < 128) { lRowS[t] = 0.f; lColS[t] = 0.f; lRowK[t] = 0ull; lColK[t] = 0ull; }

    floatx4 acc[4][2] = {};
    // ---- pipelined 3-split x 2 chunks (hh, hl, lh per chunk) ----
    stageBuf(gA, A0, 0, 0, t); stageBuf(gB, B0, 0, 0, t);      // c0 Ah, Bh
    __syncthreads();
    stageBuf(gA, A1, 0, 1, t); stageBuf(gB, B1, 0, 1, t);      // c0 Al, Bl
    computeSplit(A0, B0, lane, wr, wc, acc);                   // c0 hh
    __syncthreads();
    computeSplit(A0, B1, lane, wr, wc, acc);                   // c0 hl
    __syncthreads();
    stageBuf(gA, A0, 1, 0, t); stageBuf(gB, B1, 1, 0, t);      // c1 Ah, Bh
    computeSplit(A1, B0, lane, wr, wc, acc);                   // c0 lh
    __syncthreads();
    stageBuf(gA, A1, 1, 1, t); stageBuf(gB, B0, 1, 1, t);      // c1 Al, Bl
    computeSplit(A0, B1, lane, wr, wc, acc);                   // c1 hh
    __syncthreads();
    computeSplit(A0, B0, lane, wr, wc, acc);                   // c1 hl
    computeSplit(A1, B1, lane, wr, wc, acc);                   // c1 lh

    // ---- epilogue ----
    const int l15 = lane & 15;
    const int q   = lane >> 4;
    const float iT = *invT;
    float s1r[4];
    #pragma unroll
    for (int mi = 0; mi < 4; ++mi)
        s1r[mi] = sq1[rowBase + wr * 64 + mi * 16 + l15] + EPSQ;
    const int colLoc0 = wc * 32 + q * 4;
    float4 s2v[2];
    #pragma unroll
    for (int ni = 0; ni < 2; ++ni)
        s2v[ni] = *(const float4*)(sq2 + colBase + colLoc0 + ni * 16);

    float rs[4], rv[4]; int rj[4];
    float cs[2][4], cv[2][4]; int ci[2][4];
    #pragma unroll
    for (int ni = 0; ni < 2; ++ni)
        #pragma unroll
        for (int r = 0; r < 4; ++r) { cs[ni][r] = 0.f; cv[ni][r] = -1e30f; ci[ni][r] = 0; }

    #pragma unroll
    for (int mi = 0; mi < 4; ++mi) {
        const int gi = rowBase + wr * 64 + mi * 16 + l15;
        rs[mi] = 0.f; rv[mi] = -1e30f; rj[mi] = 0;
        #pragma unroll
        for (int ni = 0; ni < 2; ++ni) {
            #pragma unroll
            for (int r = 0; r < 4; ++r) {
                float sv2 = (r == 0) ? s2v[ni].x : (r == 1) ? s2v[ni].y
                          : (r == 2) ? s2v[ni].z : s2v[ni].w;
                float dd = s1r[mi] + sv2 - 2.0f * acc[mi][ni][r];
                float v = -iT * __builtin_amdgcn_sqrtf(fmaxf(dd, EPSQ));
                float e = __expf(v);
                rs[mi] += e;
                if (v > rv[mi]) { rv[mi] = v; rj[mi] = colBase + colLoc0 + ni * 16 + r; }
                cs[ni][r] += e;
                if (v > cv[ni][r]) { cv[ni][r] = v; ci[ni][r] = gi; }   // mi asc -> first occ
            }
        }
    }

    // row reduce across col-quarters (masks 16,32): sum, max, then min-idx of ties
    #pragma unroll
    for (int mi = 0; mi < 4; ++mi) {
        float s = rs[mi];
        s += __shfl_xor(s, 16, 64); s += __shfl_xor(s, 32, 64);
        float v = rv[mi];
        v = fmaxf(v, __shfl_xor(v, 16, 64)); v = fmaxf(v, __shfl_xor(v, 32, 64));
        int cand = (rv[mi] == v) ? rj[mi] : 0x7FFFFFFF;
        cand = min(cand, __shfl_xor(cand, 16, 64));
        cand = min(cand, __shfl_xor(cand, 32, 64));
        if (lane < 16) {
            int idx = wr * 64 + mi * 16 + l15;
            atomicAdd(&lRowS[idx], s);
            atomicMax(&lRowK[idx], makeKey(v, cand));
        }
    }

    // col reduce across l15 lanes: DPP rotate-reduce within the 16-lane DPP row
    #pragma unroll
    for (int ni = 0; ni < 2; ++ni)
        #pragma unroll
        for (int r = 0; r < 4; ++r) {
            float s = cs[ni][r];
            s += DPPF(s, ROR8); s += DPPF(s, ROR4); s += DPPF(s, ROR2); s += DPPF(s, ROR1);
            float v = cv[ni][r];
            v = fmaxf(v, DPPF(v, ROR8)); v = fmaxf(v, DPPF(v, ROR4));
            v = fmaxf(v, DPPF(v, ROR2)); v = fmaxf(v, DPPF(v, ROR1));
            int cand = (cv[ni][r] == v) ? ci[ni][r] : 0x7FFFFFFF;
            cand = min(cand, DPPI(cand, ROR8)); cand = min(cand, DPPI(cand, ROR4));
            cand = min(cand, DPPI(cand, ROR2)); cand = min(cand, DPPI(cand, ROR1));
            if (l15 == 0) {
                int idx = colLoc0 + ni * 16 + r;
                atomicAdd(&lColS[idx], s);
                atomicMax(&lColK[idx], makeKey(v, cand));
            }
        }
    __syncthreads();

    if (t < 128) {
        atomicAdd(&rowsum[rowBase + t], lRowS[t]);
        atomicMax(&rowkey[rowBase + t], lRowK[t]);
    } else if (t < 256) {
        int j = t - 128;
        atomicAdd(&colsum[colBase + j], lColS[j]);
        atomicMax(&colkey[colBase + j], lColK[j]);
    }
}

// ---------------- K2: per-row/col LSE + matches + cycle (merged) ------------
__global__ __launch_bounds__(256) void finalize_small_kernel(
    const float* __restrict__ rowsum, const ull* __restrict__ rowkey,
    const float* __restrict__ colsum, const ull* __restrict__ colkey,
    float* __restrict__ rowlse, float* __restrict__ collse,
    float* __restrict__ out_matches, float* __restrict__ out_cyc)
{
    int i = blockIdx.x * 256 + threadIdx.x;      // N == M
    if (i >= NROWS) return;
    rowlse[i] = logf(rowsum[i]);
    collse[i] = logf(colsum[i]);
    int mi = decodeKeyIdx(rowkey[i]);
    out_matches[i]         = (float)i;
    out_matches[NROWS + i] = (float)mi;
    out_cyc[i] = (decodeKeyIdx(colkey[mi]) == i) ? 1.0f : 0.0f;
}

// ---------------- K3: 2-split GEMM (pipelined) -> write logp + p ------------
__global__ __launch_bounds__(512, 4) void gemm_write_kernel(
    const unsigned short* __restrict__ s1, const unsigned short* __restrict__ s2,
    const float* __restrict__ invT,
    const float* __restrict__ sq1, const float* __restrict__ sq2,
    const float* __restrict__ rowlse, const float* __restrict__ collse,
    float* __restrict__ logp_out, float* __restrict__ p_out)
{
    __shared__ unsigned short A0[8192], A1[8192], B0[8192], B1[8192];  // 4x16KB

    const int t = threadIdx.x;
    const int lane = t & 63;
    const int wave = t >> 6;
    const int wr = wave >> 2, wc = wave & 3;
    int rowBase, colBase;
    tileCoord(rowBase, colBase);
    const unsigned short* gA = s1 + (size_t)rowBase * 256;
    const unsigned short* gB = s2 + (size_t)colBase * 256;

    floatx4 acc[4][2] = {};
    // ---- pipelined 2-split (a*bh = ah*bh + al*bh) x 2 chunks ----
    stageBuf(gA, A0, 0, 0, t); stageBuf(gB, B0, 0, 0, t);      // c0 Ah, Bh
    __syncthreads();
    stageBuf(gA, A1, 0, 1, t); stageBuf(gB, B1, 1, 0, t);      // c0 Al, c1 Bh
    computeSplit(A0, B0, lane, wr, wc, acc);                   // c0 hh
    __syncthreads();
    stageBuf(gA, A0, 1, 0, t);                                 // c1 Ah
    computeSplit(A1, B0, lane, wr, wc, acc);                   // c0 lh
    __syncthreads();
    stageBuf(gA, A1, 1, 1, t);                                 // c1 Al
    computeSplit(A0, B1, lane, wr, wc, acc);                   // c1 hh
    __syncthreads();
    computeSplit(A1, B1, lane, wr, wc, acc);                   // c1 lh

    const int l15 = lane & 15;
    const int q   = lane >> 4;
    const float iT = *invT;
    float s1r[4], rl[4];
    #pragma unroll
    for (int mi = 0; mi < 4; ++mi) {
        int gi = rowBase + wr * 64 + mi * 16 + l15;
        s1r[mi] = sq1[gi] + EPSQ;
        rl[mi]  = rowlse[gi];
    }
    const int colLoc0 = wc * 32 + q * 4;
    float4 s2v[2], clv[2];
    #pragma unroll
    for (int ni = 0; ni < 2; ++ni) {
        s2v[ni] = *(const float4*)(sq2    + colBase + colLoc0 + ni * 16);
        clv[ni] = *(const float4*)(collse + colBase + colLoc0 + ni * 16);
    }

    #pragma unroll
    for (int mi = 0; mi < 4; ++mi) {
        const int gi = rowBase + wr * 64 + mi * 16 + l15;
        #pragma unroll
        for (int ni = 0; ni < 2; ++ni) {
            floatx4 ov, pv;
            #pragma unroll
            for (int r = 0; r < 4; ++r) {
                float sv2 = (r == 0) ? s2v[ni].x : (r == 1) ? s2v[ni].y
                          : (r == 2) ? s2v[ni].z : s2v[ni].w;
                float cl  = (r == 0) ? clv[ni].x : (r == 1) ? clv[ni].y
                          : (r == 2) ? clv[ni].z : clv[ni].w;
                float dd = s1r[mi] + sv2 - 2.0f * acc[mi][ni][r];
                float v = -iT * __builtin_amdgcn_sqrtf(fmaxf(dd, EPSQ));
                float o = (v - rl[mi]) + (v - cl);
                ov[r] = o;
                pv[r] = __expf(o);
            }
            size_t off = (size_t)gi * MCOLS + colBase + colLoc0 + ni * 16;
            __builtin_nontemporal_store(ov, (floatx4*)(logp_out + off));
            __builtin_nontemporal_store(pv, (floatx4*)(p_out + off));
        }
    }
}

extern "C" void kernel_launch(void* const* d_in, const int* in_sizes, int n_in,
                              void* d_out, int out_size, void* d_ws, size_t ws_size,
                              hipStream_t stream) {
    const float* d1   = (const float*)d_in[0];
    const float* d2   = (const float*)d_in[1];
    const float* invT = (const float*)d_in[2];

    float* out     = (float*)d_out;
    float* logp    = out;
    float* pout    = out + (size_t)NROWS * MCOLS;
    float* matches = out + 2ull * NROWS * MCOLS;
    float* cyc     = matches + 2 * NROWS;

    char* ws = (char*)d_ws;
    float* rowsum = (float*)(ws + 0);
    float* colsum = (float*)(ws + 24576);
    ull*   rowkey = (ull*)(ws + 49152);
    ull*   colkey = (ull*)(ws + 98304);
    float* sq1    = (float*)(ws + 147456);
    float* sq2    = (float*)(ws + 172032);
    float* rowlse = (float*)(ws + 196608);
    float* collse = (float*)(ws + 221184);
    unsigned short* s1 = (unsigned short*)(ws + 270336);            // [N][256] bf16
    unsigned short* s2 = (unsigned short*)(ws + 270336 + 3145728);  // [M][256] bf16

    convert_kernel<<<(NROWS + MCOLS) / 4, 256, 0, stream>>>(
        d1, d2, s1, s2, sq1, sq2, (unsigned*)ws);

    gemm_reduce_kernel<<<NTC * NTC, 512, 0, stream>>>(
        s1, s2, invT, sq1, sq2, rowsum, colsum, rowkey, colkey);

    finalize_small_kernel<<<NROWS / 256, 256, 0, stream>>>(
        rowsum, rowkey, colsum, colkey, rowlse, collse, matches, cyc);

    gemm_write_kernel<<<NTC * NTC, 512, 0, stream>>>(
        s1, s2, invT, sq1, sq2, rowlse, collse, logp, pout);
}